// Round 11
// baseline (377.306 us; speedup 1.0000x reference)
//
#include <hip/hip_runtime.h>
#include <hip/hip_bf16.h>

typedef __attribute__((ext_vector_type(8))) __bf16 bf16x8;
typedef __attribute__((ext_vector_type(4))) __bf16 bf16x4;
typedef __attribute__((ext_vector_type(4))) float f32x4;

#define B_ROWS 16384
#define LDF 2560
#define BN_EPS 1e-5f

__device__ __forceinline__ void async16(void* lds, const void* g) {
  __builtin_amdgcn_global_load_lds(
      (const __attribute__((address_space(1))) unsigned int*)g,
      (__attribute__((address_space(3))) unsigned int*)lds, 16, 0, 0);
}

__device__ __forceinline__ bf16x8 cvt8(float4 a, float4 b) {
  bf16x8 t;
  t[0] = (__bf16)a.x; t[1] = (__bf16)a.y; t[2] = (__bf16)a.z; t[3] = (__bf16)a.w;
  t[4] = (__bf16)b.x; t[5] = (__bf16)b.y; t[6] = (__bf16)b.z; t[7] = (__bf16)b.w;
  return t;
}

// Split-K partial GEMM -> bf16 partial planes.
// Tile 128x128, BK=32, 4 waves (2x2), wave-tile 64x64, acc 4x4 (32 FLOP/LDS-byte).
// 3-buffer LDS (48KB -> 3 blocks/CU, grid 768 fully resident = 12 waves/CU).
// STAGE = 4 global_load_lds; at loop top tiles t,t+1 in flight (8 loads);
// vmcnt(4) completes tile t. Tile t+2 staged into buf (t+2)%3 != {t,t+1}%3 (no race).
// wgid -> sk = wgid%skmod (partners adjacent -> same XCD chunk), tile = wgid/skmod.
// kl = min(Ksplit, Kd-k0) handles non-divisible K (last sk shorter).
__global__ __launch_bounds__(256) void gemm_sk(
    const __bf16* __restrict__ A, const __bf16* __restrict__ W,
    __bf16* __restrict__ Cplanes, int Kd, int Ksplit, int ldc,
    int skmod, int bxbits)
{
  __shared__ __bf16 lds[3][8192];

  const int tid  = threadIdx.x;
  const int lane = tid & 63;
  const int wid  = tid >> 6;
  const int wm   = wid >> 1, wn = wid & 1;
  const int fr   = lane & 15, fk = lane >> 4;

  const int cpx  = gridDim.x >> 3;
  const int wgid = (blockIdx.x & 7) * cpx + (blockIdx.x >> 3);
  const int sk   = wgid % skmod;
  const int tile = wgid / skmod;
  const int bx   = tile & ((1 << bxbits) - 1);
  const int by   = tile >> bxbits;
  const int bn0  = bx * 128, bm0 = by * 128;
  const int k0   = sk * Ksplit;
  const int kl   = min(Ksplit, Kd - k0);
  const int NT   = kl >> 5;

  // staging: group j (j=0..3) rows j*64+(tid>>2), slot tid&3.
  // Source k-chunk pre-swizzled: LDS[row][slot] holds chunk (slot ^ ((row>>1)&3)).
  const int srow = tid >> 2;
  const int sko  = ((tid & 3) ^ ((tid >> 3) & 3)) << 3;  // elems
  const __bf16* a0p = A + (size_t)(bm0 + srow) * LDF + k0 + sko;
  const __bf16* a1p = a0p + (size_t)64 * LDF;
  const __bf16* b0p = W + (size_t)(bn0 + srow) * Kd + k0 + sko;
  const __bf16* b1p = b0p + (size_t)64 * Kd;

#define STAGE(b, kt) do {                                           \
    async16((void*)(&lds[b][(size_t)tid * 8]),         a0p + (kt)); \
    async16((void*)(&lds[b][(size_t)(256 + tid) * 8]), a1p + (kt)); \
    async16((void*)(&lds[b][(size_t)(512 + tid) * 8]), b0p + (kt)); \
    async16((void*)(&lds[b][(size_t)(768 + tid) * 8]), b1p + (kt)); \
  } while (0)

  // fragment read offsets (loop-invariant): elem = r*32 + (fk ^ ((r>>1)&3))*8
  int aoff[4], boff[4];
#pragma unroll
  for (int i = 0; i < 4; ++i) {
    int ra = wm * 64 + i * 16 + fr;
    aoff[i] = ra * 32 + ((fk ^ ((ra >> 1) & 3)) << 3);
    int rb = wn * 64 + i * 16 + fr;
    boff[i] = 4096 + rb * 32 + ((fk ^ ((rb >> 1) & 3)) << 3);
  }

  f32x4 acc[4][4] = {};

  STAGE(0, 0);
  STAGE(1, 32);

  int rb = 0;  // buffer holding tile t
  for (int t = 0; t < NT; ++t) {
    if (t < NT - 1) asm volatile("s_waitcnt vmcnt(4)" ::: "memory");
    else            asm volatile("s_waitcnt vmcnt(0)" ::: "memory");
    __builtin_amdgcn_s_barrier();
    __builtin_amdgcn_sched_barrier(0);

    if (t + 2 < NT) {
      int sb = rb + 2; if (sb >= 3) sb -= 3;
      STAGE(sb, (t + 2) * 32);
    }
    __builtin_amdgcn_sched_barrier(0);

    const __bf16* bp = lds[rb];
    bf16x8 af[4], bf[4];
#pragma unroll
    for (int i = 0; i < 4; ++i) af[i] = *(const bf16x8*)(bp + aoff[i]);
#pragma unroll
    for (int i = 0; i < 4; ++i) bf[i] = *(const bf16x8*)(bp + boff[i]);
#pragma unroll
    for (int mi = 0; mi < 4; ++mi)
#pragma unroll
      for (int ni = 0; ni < 4; ++ni)
        acc[mi][ni] = __builtin_amdgcn_mfma_f32_16x16x32_bf16(af[mi], bf[ni], acc[mi][ni], 0, 0, 0);

    if (++rb == 3) rb = 0;
  }
#undef STAGE

  __bf16* Cp = Cplanes + (size_t)sk * B_ROWS * ldc;
#pragma unroll
  for (int mi = 0; mi < 4; ++mi) {
#pragma unroll
    for (int ni = 0; ni < 4; ++ni) {
      const int row0 = bm0 + wm * 64 + mi * 16 + fk * 4;
      const int col  = bn0 + wn * 64 + ni * 16 + fr;
      __bf16* cp = Cp + (size_t)row0 * ldc + col;
#pragma unroll
      for (int r = 0; r < 4; ++r)
        cp[(size_t)r * ldc] = (__bf16)acc[mi][ni][r];
    }
  }
}

// Stage epilogue: h = relu(sum of 3 bf16 planes + badj) -> bf16 feats col-block
// + col stats. 256 blocks x 64 rows.
__global__ __launch_bounds__(256) void epi_stage(
    const __bf16* __restrict__ P, const float* __restrict__ badj,
    __bf16* __restrict__ hout,
    float* __restrict__ colsum, float* __restrict__ colsumsq)
{
  const int tid = threadIdx.x;
  const int c8  = (tid & 31) * 8;
  const int rg  = tid >> 5;
  const int r0  = blockIdx.x * 64 + rg;
  const size_t PL = (size_t)B_ROWS * 256;
  float bv[8];
  *(float4*)bv       = *(const float4*)(badj + c8);
  *(float4*)(bv + 4) = *(const float4*)(badj + c8 + 4);
  float ps[8] = {}, pq[8] = {};
#pragma unroll 2
  for (int i = 0; i < 8; ++i) {
    int r = r0 + i * 8;
    const __bf16* p = P + (size_t)r * 256 + c8;
    bf16x8 p0 = *(const bf16x8*)p;
    bf16x8 p1 = *(const bf16x8*)(p + PL);
    bf16x8 p2 = *(const bf16x8*)(p + 2 * PL);
    bf16x8 o;
#pragma unroll
    for (int j = 0; j < 8; ++j) {
      float v = fmaxf((float)p0[j] + (float)p1[j] + (float)p2[j] + bv[j], 0.f);
      ps[j] += v; pq[j] += v * v;
      o[j] = (__bf16)v;
    }
    *(bf16x8*)(hout + (size_t)r * LDF + c8) = o;
  }
  __shared__ float ls[256], lq[256];
  ls[tid] = 0.f; lq[tid] = 0.f;
  __syncthreads();
#pragma unroll
  for (int j = 0; j < 8; ++j) {
    atomicAdd(&ls[c8 + j], ps[j]);
    atomicAdd(&lq[c8 + j], pq[j]);
  }
  __syncthreads();
  atomicAdd(&colsum[tid], ls[tid]);
  atomicAdd(&colsumsq[tid], lq[tid]);
}

// Final epilogue: out = sum of 6 bf16 planes (pitch 128) + badj -> fp32
__global__ __launch_bounds__(256) void epi_final(
    const __bf16* __restrict__ P, const float* __restrict__ badj,
    float* __restrict__ out)
{
  int idx = blockIdx.x * 256 + threadIdx.x;   // grid 1024 -> 262144 threads
  int r = idx >> 4, c8 = (idx & 15) * 8;
  const size_t PL = (size_t)B_ROWS * 128;
  const __bf16* p = P + (size_t)r * 128 + c8;
  float s[8];
  *(float4*)s       = *(const float4*)(badj + c8);
  *(float4*)(s + 4) = *(const float4*)(badj + c8 + 4);
#pragma unroll
  for (int sk = 0; sk < 6; ++sk) {
    bf16x8 v = *(const bf16x8*)(p + (size_t)sk * PL);
#pragma unroll
    for (int j = 0; j < 8; ++j) s[j] += (float)v[j];
  }
  float* op = out + (size_t)r * 128 + c8;
  *(float4*)op       = *(float4*)s;
  *(float4*)(op + 4) = *(float4*)(s + 4);
}

__global__ void cast_x_kernel(const float* __restrict__ x, __bf16* __restrict__ feats) {
  int idx = blockIdx.x * blockDim.x + threadIdx.x;  // B_ROWS*64 threads
  int row = idx >> 6, c8 = (idx & 63) << 3;
  const float4* xp = (const float4*)(x + (size_t)row * 512 + c8);
  float4 a = xp[0], b = xp[1];
  *(bf16x8*)(feats + (size_t)row * LDF + c8) = cvt8(a, b);
}

// Fused fp32->bf16 W-cast with BN folded: W'[n,c]=W[n,c]*sc[c]; badj[n]=bias[n]+sum_c sh[c]*W[n,c]
__global__ void prep_w(const float* __restrict__ W, const float* __restrict__ bias,
                       const float* __restrict__ colsum, const float* __restrict__ colsumsq,
                       const float* __restrict__ gamma, const float* __restrict__ beta,
                       __bf16* __restrict__ Wb, float* __restrict__ badj, int Kd)
{
  const int n = blockIdx.x, t = threadIdx.x;  // 256 threads per row
  const float invB = 1.0f / 16384.0f;
  float accb = 0.f;
  for (int c0 = t * 4; c0 < Kd; c0 += 1024) {
    float4 w = *(const float4*)(W + (size_t)n * Kd + c0);
    float wv[4] = {w.x, w.y, w.z, w.w};
    bf16x4 o;
#pragma unroll
    for (int i = 0; i < 4; ++i) {
      int c = c0 + i;
      float sc = 1.f, sh = 0.f;
      if (c >= 512) {
        int idx = c - 512;
        float mu  = colsum[idx] * invB;
        float var = colsumsq[idx] * invB - mu * mu;
        sc = gamma[idx] * rsqrtf(var + BN_EPS);
        sh = beta[idx] - mu * sc;
      }
      accb += wv[i] * sh;
      o[i] = (__bf16)(wv[i] * sc);
    }
    *(bf16x4*)(Wb + (size_t)n * Kd + c0) = o;
  }
  __shared__ float red[256];
  red[t] = accb;
  __syncthreads();
  for (int s = 128; s > 0; s >>= 1) {
    if (t < s) red[t] += red[t + s];
    __syncthreads();
  }
  if (t == 0) badj[n] = bias[n] + red[0];
}

extern "C" void kernel_launch(void* const* d_in, const int* in_sizes, int n_in,
                              void* d_out, int out_size, void* d_ws, size_t ws_size,
                              hipStream_t stream) {
  const float* x = (const float*)d_in[0];
  const float* Wi[8];
  for (int i = 0; i < 8; ++i) Wi[i] = (const float*)d_in[1 + i];
  const float* b     = (const float*)d_in[9];
  const float* gamma = (const float*)d_in[10];
  const float* beta  = (const float*)d_in[11];
  const float* Wout  = (const float*)d_in[12];
  const float* bout  = (const float*)d_in[13];
  float* out = (float*)d_out;

  char* ws = (char*)d_ws;
  __bf16* feats = (__bf16*)ws;
  size_t off = (size_t)B_ROWS * LDF * 2;
  __bf16* wb[8];
  {
    int d = 512;
    for (int i = 0; i < 8; ++i) { wb[i] = (__bf16*)(ws + off); off += (size_t)256 * d * 2; d += 256; }
  }
  __bf16* woutb = (__bf16*)(ws + off); off += (size_t)128 * 2560 * 2;
  // partial planes: max(3*16384*256, 6*16384*128) = 12.58M bf16 = 25.2 MB
  __bf16* planes = (__bf16*)(ws + off); off += (size_t)3 * B_ROWS * 256 * 2;
  float* colsum   = (float*)(ws + off); off += 8 * 256 * 4;
  float* colsumsq = (float*)(ws + off); off += 8 * 256 * 4;
  float* badj     = (float*)(ws + off); off += 9 * 256 * 4;

  hipMemsetAsync(colsum, 0, 2 * 8 * 256 * 4, stream);

  cast_x_kernel<<<B_ROWS * 64 / 256, 256, 0, stream>>>(x, feats);

  int d = 512;
  for (int i = 0; i < 8; ++i) {
    prep_w<<<256, 256, 0, stream>>>(Wi[i], b + i * 256, colsum, colsumsq,
                                    gamma, beta, wb[i], badj + i * 256, d);
    int kspl = 32 * ((d / 3 + 31) / 32);       // SK=3, last sk takes remainder
    // grid = 2 bx * 128 by * 3 sk = 768 (3 blocks/CU, fully resident)
    gemm_sk<<<768, 256, 0, stream>>>(feats, wb[i], planes, d, kspl, 256, 3, 1);
    epi_stage<<<256, 256, 0, stream>>>(planes, badj + i * 256, feats + d,
                                       colsum + i * 256, colsumsq + i * 256);
    d += 256;
  }
  prep_w<<<128, 256, 0, stream>>>(Wout, bout, colsum, colsumsq,
                                  gamma, beta, woutb, badj + 8 * 256, 2560);
  // final: bxbits=0, SK=6 (Ksplit=448, last=320): grid = 128 by * 6 = 768
  gemm_sk<<<768, 256, 0, stream>>>(feats, woutb, planes, 2560, 448, 128, 6, 0);
  epi_final<<<1024, 256, 0, stream>>>(planes, badj + 8 * 256, out);
}

// Round 12
// 302.272 us; speedup vs baseline: 1.2482x; 1.2482x over previous
//
#include <hip/hip_runtime.h>
#include <hip/hip_bf16.h>

typedef __attribute__((ext_vector_type(8))) __bf16 bf16x8;
typedef __attribute__((ext_vector_type(4))) __bf16 bf16x4;
typedef __attribute__((ext_vector_type(4))) float f32x4;

#define B_ROWS 16384
#define LDF 2560
#define BN_EPS 1e-5f

__device__ __forceinline__ void async16(void* lds, const void* g) {
  __builtin_amdgcn_global_load_lds(
      (const __attribute__((address_space(1))) unsigned int*)g,
      (__attribute__((address_space(3))) unsigned int*)lds, 16, 0, 0);
}

__device__ __forceinline__ bf16x8 cvt8(float4 a, float4 b) {
  bf16x8 t;
  t[0] = (__bf16)a.x; t[1] = (__bf16)a.y; t[2] = (__bf16)a.z; t[3] = (__bf16)a.w;
  t[4] = (__bf16)b.x; t[5] = (__bf16)b.y; t[6] = (__bf16)b.z; t[7] = (__bf16)b.w;
  return t;
}

// C-tile = A(bf16,[B_ROWS,LDF]) x W(bf16,[Ntot,Kd])^T (+badj in epilogue)
// BM=64 x BN=128, BK=64, 4 waves (2x2), wave-tile 32x64, acc 2x4, 16 MFMA/iter.
// 3-buffer LDS (72KB -> 2 blocks/CU), prefetch depth 2.
// STAGE = 6 global_load_lds; loop top has tiles t,t+1 in flight (12 loads);
// vmcnt(6) completes exactly tile t. Tile t+2 -> buf (rb+2)%3 (no overlap).
// LDS row = 64 elems (8 slots of 8); slot holds k-chunk (slot ^ (row&7)) via
// pre-swizzled source; fragment read slot = kc ^ (row&7) -> 2 lanes/bank (free).
// Grid 1-D, XCD-chunked swizzle (gridDim%8==0): wgid -> (bx, sk, by).
// mode 1 (skbits=0): h=relu(acc+badj) -> bf16 hout (stride LDF) + col stats.
// mode 0: fp32 partial into Cpart[sk] (ldc=128).
__global__ __launch_bounds__(256) void gemm_stage(
    const __bf16* __restrict__ A, const __bf16* __restrict__ W,
    const float* __restrict__ badj,
    __bf16* __restrict__ hout, float* __restrict__ Cpart,
    float* __restrict__ colsum, float* __restrict__ colsumsq,
    int Kd, int Ksplit, int mode, int bxbits, int skbits)
{
  __shared__ __bf16 lds[3][12288];  // per buf: A 64x64 (4096) + B 128x64 (8192)

  const int tid  = threadIdx.x;
  const int lane = tid & 63;
  const int wid  = tid >> 6;
  const int wm   = wid >> 1, wn = wid & 1;
  const int fr   = lane & 15, fk = lane >> 4;

  const int cpx  = gridDim.x >> 3;
  const int wgid = (blockIdx.x & 7) * cpx + (blockIdx.x >> 3);
  const int bx   = wgid & ((1 << bxbits) - 1);
  const int sk   = (wgid >> bxbits) & ((1 << skbits) - 1);
  const int by   = wgid >> (bxbits + skbits);
  const int bn0  = bx * 128, bm0 = by * 64;
  const int k0   = sk * Ksplit;

  // staging: chunk row = chunkbase + (tid>>3), slot = tid&7 (linear dest).
  // Source k-chunk pre-swizzled: ko = slot ^ ((tid>>3)&7)  (chunkbase%8==0).
  const int srow = tid >> 3;
  const int sko  = ((tid & 7) ^ (srow & 7)) << 3;  // elems
  const __bf16* a0p = A + (size_t)(bm0 + srow) * LDF + k0 + sko;
  const __bf16* a1p = a0p + (size_t)32 * LDF;
  const __bf16* b0p = W + (size_t)(bn0 + srow) * Kd + k0 + sko;
  const __bf16* b1p = b0p + (size_t)32 * Kd;
  const __bf16* b2p = b0p + (size_t)64 * Kd;
  const __bf16* b3p = b0p + (size_t)96 * Kd;

#define STAGE(b, kt) do {                                            \
    async16((void*)(&lds[b][(size_t)tid * 8]),          a0p + (kt)); \
    async16((void*)(&lds[b][(size_t)(2048 + tid * 8)]), a1p + (kt)); \
    async16((void*)(&lds[b][(size_t)(4096 + tid * 8)]), b0p + (kt)); \
    async16((void*)(&lds[b][(size_t)(6144 + tid * 8)]), b1p + (kt)); \
    async16((void*)(&lds[b][(size_t)(8192 + tid * 8)]), b2p + (kt)); \
    async16((void*)(&lds[b][(size_t)(10240 + tid * 8)]), b3p + (kt));\
  } while (0)

  // fragment read offsets (loop-invariant): elem = r*64 + ((kc ^ (r&7))<<3)
  int aoff[2][2], boff[2][4];
#pragma unroll
  for (int ksub = 0; ksub < 2; ++ksub) {
    const int kc = ksub * 4 + fk;
#pragma unroll
    for (int i = 0; i < 2; ++i) {
      int ra = wm * 32 + i * 16 + fr;
      aoff[ksub][i] = ra * 64 + ((kc ^ (ra & 7)) << 3);
    }
#pragma unroll
    for (int i = 0; i < 4; ++i) {
      int rb2 = wn * 64 + i * 16 + fr;
      boff[ksub][i] = 4096 + rb2 * 64 + ((kc ^ (rb2 & 7)) << 3);
    }
  }

  f32x4 acc[2][4] = {};

  const int NT = Ksplit >> 6;
  STAGE(0, 0);
  STAGE(1, 64);

  int rb = 0;
  for (int t = 0; t < NT; ++t) {
    if (t < NT - 1) asm volatile("s_waitcnt vmcnt(6)" ::: "memory");
    else            asm volatile("s_waitcnt vmcnt(0)" ::: "memory");
    __builtin_amdgcn_s_barrier();
    __builtin_amdgcn_sched_barrier(0);

    if (t + 2 < NT) {
      int sb = rb + 2; if (sb >= 3) sb -= 3;
      STAGE(sb, (t + 2) * 64);
    }
    __builtin_amdgcn_sched_barrier(0);

    const __bf16* bp = lds[rb];
#pragma unroll
    for (int ksub = 0; ksub < 2; ++ksub) {
      bf16x8 af[2], bf[4];
#pragma unroll
      for (int i = 0; i < 2; ++i) af[i] = *(const bf16x8*)(bp + aoff[ksub][i]);
#pragma unroll
      for (int i = 0; i < 4; ++i) bf[i] = *(const bf16x8*)(bp + boff[ksub][i]);
#pragma unroll
      for (int mi = 0; mi < 2; ++mi)
#pragma unroll
        for (int ni = 0; ni < 4; ++ni)
          acc[mi][ni] = __builtin_amdgcn_mfma_f32_16x16x32_bf16(af[mi], bf[ni], acc[mi][ni], 0, 0, 0);
    }

    if (++rb == 3) rb = 0;
  }
#undef STAGE

  if (mode) {
    float psum[4] = {0.f, 0.f, 0.f, 0.f}, psq[4] = {0.f, 0.f, 0.f, 0.f};
#pragma unroll
    for (int mi = 0; mi < 2; ++mi) {
#pragma unroll
      for (int ni = 0; ni < 4; ++ni) {
        const int col  = bn0 + wn * 64 + ni * 16 + fr;
        const int row0 = bm0 + wm * 32 + mi * 16 + fk * 4;
        const float bv = badj[col];
        __bf16* hp = hout + (size_t)row0 * LDF + col;
#pragma unroll
        for (int r = 0; r < 4; ++r) {
          float v = fmaxf(acc[mi][ni][r] + bv, 0.f);
          psum[ni] += v; psq[ni] += v * v;
          hp[(size_t)r * LDF] = (__bf16)v;
        }
      }
    }
#pragma unroll
    for (int ni = 0; ni < 4; ++ni) {
      float s = psum[ni], q = psq[ni];
      s += __shfl_xor(s, 16); s += __shfl_xor(s, 32);
      q += __shfl_xor(q, 16); q += __shfl_xor(q, 32);
      if (fk == 0) {
        int col = bn0 + wn * 64 + ni * 16 + fr;
        atomicAdd(&colsum[col], s);
        atomicAdd(&colsumsq[col], q);
      }
    }
  } else {
    float* Cp = Cpart + (size_t)sk * B_ROWS * 128;
#pragma unroll
    for (int mi = 0; mi < 2; ++mi) {
#pragma unroll
      for (int ni = 0; ni < 4; ++ni) {
        const int col  = bn0 + wn * 64 + ni * 16 + fr;
        const int row0 = bm0 + wm * 32 + mi * 16 + fk * 4;
        float* cp = Cp + (size_t)row0 * 128 + col;
#pragma unroll
        for (int r = 0; r < 4; ++r)
          cp[(size_t)r * 128] = acc[mi][ni][r];
      }
    }
  }
}

// Final epilogue: out = sum_{sk<4} Cpart[sk] + badj (fp32, 16384x128)
__global__ __launch_bounds__(256) void epi_final(
    const float* __restrict__ Cp, const float* __restrict__ badj,
    float* __restrict__ out)
{
  int idx = blockIdx.x * 256 + threadIdx.x;   // 524288 threads
  int r = idx >> 5, c = (idx & 31) * 4;
  const float* p = Cp + (size_t)r * 128 + c;
  const size_t pl = (size_t)B_ROWS * 128;
  float4 a = *(const float4*)p;
  float4 b = *(const float4*)(p + pl);
  float4 d2 = *(const float4*)(p + 2 * pl);
  float4 e = *(const float4*)(p + 3 * pl);
  float4 bv = *(const float4*)(badj + c);
  float4 o;
  o.x = a.x + b.x + d2.x + e.x + bv.x;
  o.y = a.y + b.y + d2.y + e.y + bv.y;
  o.z = a.z + b.z + d2.z + e.z + bv.z;
  o.w = a.w + b.w + d2.w + e.w + bv.w;
  *(float4*)(out + (size_t)r * 128 + c) = o;
}

__global__ void cast_x_kernel(const float* __restrict__ x, __bf16* __restrict__ feats) {
  int idx = blockIdx.x * blockDim.x + threadIdx.x;  // B_ROWS*64 threads
  int row = idx >> 6, c8 = (idx & 63) << 3;
  const float4* xp = (const float4*)(x + (size_t)row * 512 + c8);
  float4 a = xp[0], b = xp[1];
  *(bf16x8*)(feats + (size_t)row * LDF + c8) = cvt8(a, b);
}

// Fused fp32->bf16 W-cast with BN folded: W'[n,c]=W[n,c]*sc[c]; badj[n]=bias[n]+sum_c sh[c]*W[n,c]
__global__ void prep_w(const float* __restrict__ W, const float* __restrict__ bias,
                       const float* __restrict__ colsum, const float* __restrict__ colsumsq,
                       const float* __restrict__ gamma, const float* __restrict__ beta,
                       __bf16* __restrict__ Wb, float* __restrict__ badj, int Kd)
{
  const int n = blockIdx.x, t = threadIdx.x;  // 256 threads per row
  const float invB = 1.0f / 16384.0f;
  float accb = 0.f;
  for (int c0 = t * 4; c0 < Kd; c0 += 1024) {
    float4 w = *(const float4*)(W + (size_t)n * Kd + c0);
    float wv[4] = {w.x, w.y, w.z, w.w};
    bf16x4 o;
#pragma unroll
    for (int i = 0; i < 4; ++i) {
      int c = c0 + i;
      float sc = 1.f, sh = 0.f;
      if (c >= 512) {
        int idx = c - 512;
        float mu  = colsum[idx] * invB;
        float var = colsumsq[idx] * invB - mu * mu;
        sc = gamma[idx] * rsqrtf(var + BN_EPS);
        sh = beta[idx] - mu * sc;
      }
      accb += wv[i] * sh;
      o[i] = (__bf16)(wv[i] * sc);
    }
    *(bf16x4*)(Wb + (size_t)n * Kd + c0) = o;
  }
  __shared__ float red[256];
  red[t] = accb;
  __syncthreads();
  for (int s = 128; s > 0; s >>= 1) {
    if (t < s) red[t] += red[t + s];
    __syncthreads();
  }
  if (t == 0) badj[n] = bias[n] + red[0];
}

extern "C" void kernel_launch(void* const* d_in, const int* in_sizes, int n_in,
                              void* d_out, int out_size, void* d_ws, size_t ws_size,
                              hipStream_t stream) {
  const float* x = (const float*)d_in[0];
  const float* Wi[8];
  for (int i = 0; i < 8; ++i) Wi[i] = (const float*)d_in[1 + i];
  const float* b     = (const float*)d_in[9];
  const float* gamma = (const float*)d_in[10];
  const float* beta  = (const float*)d_in[11];
  const float* Wout  = (const float*)d_in[12];
  const float* bout  = (const float*)d_in[13];
  float* out = (float*)d_out;

  char* ws = (char*)d_ws;
  __bf16* feats = (__bf16*)ws;
  size_t off = (size_t)B_ROWS * LDF * 2;
  __bf16* wb[8];
  {
    int d = 512;
    for (int i = 0; i < 8; ++i) { wb[i] = (__bf16*)(ws + off); off += (size_t)256 * d * 2; d += 256; }
  }
  __bf16* woutb = (__bf16*)(ws + off); off += (size_t)128 * 2560 * 2;
  float* Cpart    = (float*)(ws + off); off += (size_t)4 * B_ROWS * 128 * 4;  // 32 MB
  float* colsum   = (float*)(ws + off); off += 8 * 256 * 4;
  float* colsumsq = (float*)(ws + off); off += 8 * 256 * 4;
  float* badj     = (float*)(ws + off); off += 9 * 256 * 4;

  hipMemsetAsync(colsum, 0, 2 * 8 * 256 * 4, stream);

  cast_x_kernel<<<B_ROWS * 64 / 256, 256, 0, stream>>>(x, feats);

  int d = 512;
  for (int i = 0; i < 8; ++i) {
    prep_w<<<256, 256, 0, stream>>>(Wi[i], b + i * 256, colsum, colsumsq,
                                    gamma, beta, wb[i], badj + i * 256, d);
    // grid = 2 bx * 256 by = 512 (2 blocks/CU)
    gemm_stage<<<512, 256, 0, stream>>>(feats, wb[i], badj + i * 256,
                                        feats + d, nullptr,
                                        colsum + i * 256, colsumsq + i * 256,
                                        d, d, 1, 1, 0);
    d += 256;
  }
  prep_w<<<128, 256, 0, stream>>>(Wout, bout, colsum, colsumsq,
                                  gamma, beta, woutb, badj + 8 * 256, 2560);
  // final: bxbits=0, SK=4 (Ksplit=640, NT=10): grid = 1 * 4 * 256 by = 1024
  gemm_stage<<<1024, 256, 0, stream>>>(feats, woutb, nullptr,
                                       nullptr, Cpart, nullptr, nullptr,
                                       2560, 640, 0, 0, 2);
  epi_final<<<2048, 256, 0, stream>>>(Cpart, badj + 8 * 256, out);
}

// Round 13
// 292.884 us; speedup vs baseline: 1.2882x; 1.0321x over previous
//
#include <hip/hip_runtime.h>
#include <hip/hip_bf16.h>

typedef __attribute__((ext_vector_type(8))) __bf16 bf16x8;
typedef __attribute__((ext_vector_type(4))) __bf16 bf16x4;
typedef __attribute__((ext_vector_type(4))) float f32x4;

#define B_ROWS 16384
#define LDF 2560
#define BN_EPS 1e-5f

__device__ __forceinline__ void async16(void* lds, const void* g) {
  __builtin_amdgcn_global_load_lds(
      (const __attribute__((address_space(1))) unsigned int*)g,
      (__attribute__((address_space(3))) unsigned int*)lds, 16, 0, 0);
}

__device__ __forceinline__ bf16x8 cvt8(float4 a, float4 b) {
  bf16x8 t;
  t[0] = (__bf16)a.x; t[1] = (__bf16)a.y; t[2] = (__bf16)a.z; t[3] = (__bf16)a.w;
  t[4] = (__bf16)b.x; t[5] = (__bf16)b.y; t[6] = (__bf16)b.z; t[7] = (__bf16)b.w;
  return t;
}

// C-tile = A(bf16,[B_ROWS,LDF]) x W(bf16,[Ntot,Kd])^T (+badj in epilogue)
// BM=64 x BN=128, BK=64, **512 threads = 8 waves (2wm x 4wn)**, wave-tile 32x32,
// acc 2x2, 8 MFMA per iter per wave. 16 waves/CU at 2 blocks/CU (72KB LDS).
// 3-buffer LDS, prefetch depth 2. STAGE = 3 gload_lds/thread; loop top has
// tiles t,t+1 in flight (6/thread); vmcnt(3) completes exactly tile t.
// LDS row = 64 elems (8 slots of 8); slot holds k-chunk (slot ^ (row&7)) via
// pre-swizzled source; read slot = kc ^ (row&7) -> 2 lanes/bank (free).
// Grid 1-D, XCD-chunked swizzle (gridDim%8==0): wgid -> (bx, sk, by).
// mode 1 (skbits=0): h=relu(acc+badj) -> bf16 hout (stride LDF) + col stats.
// mode 0: fp32 partial into Cpart[sk] (ldc=128).
__global__ __launch_bounds__(512) void gemm_stage(
    const __bf16* __restrict__ A, const __bf16* __restrict__ W,
    const float* __restrict__ badj,
    __bf16* __restrict__ hout, float* __restrict__ Cpart,
    float* __restrict__ colsum, float* __restrict__ colsumsq,
    int Kd, int Ksplit, int mode, int bxbits, int skbits)
{
  __shared__ __bf16 lds[3][12288];  // per buf: A 64x64 (4096) + B 128x64 (8192)

  const int tid  = threadIdx.x;
  const int lane = tid & 63;
  const int wid  = tid >> 6;         // 0..7
  const int wm   = wid >> 2, wn = wid & 3;
  const int fr   = lane & 15, fk = lane >> 4;

  const int cpx  = gridDim.x >> 3;
  const int wgid = (blockIdx.x & 7) * cpx + (blockIdx.x >> 3);
  const int bx   = wgid & ((1 << bxbits) - 1);
  const int sk   = (wgid >> bxbits) & ((1 << skbits) - 1);
  const int by   = wgid >> (bxbits + skbits);
  const int bn0  = bx * 128, bm0 = by * 64;
  const int k0   = sk * Ksplit;

  // staging: row = tid>>3 (0..63), slot = tid&7 (linear dest).
  // Source k-chunk pre-swizzled: ko = slot ^ (row&7).
  const int srow = tid >> 3;
  const int sko  = ((tid & 7) ^ (srow & 7)) << 3;  // elems
  const __bf16* a0p = A + (size_t)(bm0 + srow) * LDF + k0 + sko;
  const __bf16* b0p = W + (size_t)(bn0 + srow) * Kd + k0 + sko;
  const __bf16* b1p = b0p + (size_t)64 * Kd;

#define STAGE(b, kt) do {                                            \
    async16((void*)(&lds[b][(size_t)tid * 8]),          a0p + (kt)); \
    async16((void*)(&lds[b][(size_t)(4096 + tid * 8)]), b0p + (kt)); \
    async16((void*)(&lds[b][(size_t)(8192 + tid * 8)]), b1p + (kt)); \
  } while (0)

  // fragment read offsets (loop-invariant): elem = r*64 + ((kc ^ (r&7))<<3)
  int aoff[2][2], boff[2][2];
#pragma unroll
  for (int ksub = 0; ksub < 2; ++ksub) {
    const int kc = ksub * 4 + fk;
#pragma unroll
    for (int i = 0; i < 2; ++i) {
      int ra = wm * 32 + i * 16 + fr;
      aoff[ksub][i] = ra * 64 + ((kc ^ (ra & 7)) << 3);
      int rb2 = wn * 32 + i * 16 + fr;
      boff[ksub][i] = 4096 + rb2 * 64 + ((kc ^ (rb2 & 7)) << 3);
    }
  }

  f32x4 acc[2][2] = {};

  const int NT = Ksplit >> 6;
  STAGE(0, 0);
  STAGE(1, 64);

  int rb = 0;
  for (int t = 0; t < NT; ++t) {
    if (t < NT - 1) asm volatile("s_waitcnt vmcnt(3)" ::: "memory");
    else            asm volatile("s_waitcnt vmcnt(0)" ::: "memory");
    __builtin_amdgcn_s_barrier();
    __builtin_amdgcn_sched_barrier(0);

    if (t + 2 < NT) {
      int sb = rb + 2; if (sb >= 3) sb -= 3;
      STAGE(sb, (t + 2) * 64);
    }
    __builtin_amdgcn_sched_barrier(0);

    const __bf16* bp = lds[rb];
#pragma unroll
    for (int ksub = 0; ksub < 2; ++ksub) {
      bf16x8 af[2], bf[2];
#pragma unroll
      for (int i = 0; i < 2; ++i) {
        af[i] = *(const bf16x8*)(bp + aoff[ksub][i]);
        bf[i] = *(const bf16x8*)(bp + boff[ksub][i]);
      }
#pragma unroll
      for (int mi = 0; mi < 2; ++mi)
#pragma unroll
        for (int ni = 0; ni < 2; ++ni)
          acc[mi][ni] = __builtin_amdgcn_mfma_f32_16x16x32_bf16(af[mi], bf[ni], acc[mi][ni], 0, 0, 0);
    }

    if (++rb == 3) rb = 0;
  }
#undef STAGE

  if (mode) {
    float psum[2] = {0.f, 0.f}, psq[2] = {0.f, 0.f};
#pragma unroll
    for (int mi = 0; mi < 2; ++mi) {
#pragma unroll
      for (int ni = 0; ni < 2; ++ni) {
        const int col  = bn0 + wn * 32 + ni * 16 + fr;
        const int row0 = bm0 + wm * 32 + mi * 16 + fk * 4;
        const float bv = badj[col];
        __bf16* hp = hout + (size_t)row0 * LDF + col;
#pragma unroll
        for (int r = 0; r < 4; ++r) {
          float v = fmaxf(acc[mi][ni][r] + bv, 0.f);
          psum[ni] += v; psq[ni] += v * v;
          hp[(size_t)r * LDF] = (__bf16)v;
        }
      }
    }
#pragma unroll
    for (int ni = 0; ni < 2; ++ni) {
      float s = psum[ni], q = psq[ni];
      s += __shfl_xor(s, 16); s += __shfl_xor(s, 32);
      q += __shfl_xor(q, 16); q += __shfl_xor(q, 32);
      if (fk == 0) {
        int col = bn0 + wn * 32 + ni * 16 + fr;
        atomicAdd(&colsum[col], s);
        atomicAdd(&colsumsq[col], q);
      }
    }
  } else {
    float* Cp = Cpart + (size_t)sk * B_ROWS * 128;
#pragma unroll
    for (int mi = 0; mi < 2; ++mi) {
#pragma unroll
      for (int ni = 0; ni < 2; ++ni) {
        const int col  = bn0 + wn * 32 + ni * 16 + fr;
        const int row0 = bm0 + wm * 32 + mi * 16 + fk * 4;
        float* cp = Cp + (size_t)row0 * 128 + col;
#pragma unroll
        for (int r = 0; r < 4; ++r)
          cp[(size_t)r * 128] = acc[mi][ni][r];
      }
    }
  }
}

// Final epilogue: out = sum_{sk<4} Cpart[sk] + badj (fp32, 16384x128)
__global__ __launch_bounds__(256) void epi_final(
    const float* __restrict__ Cp, const float* __restrict__ badj,
    float* __restrict__ out)
{
  int idx = blockIdx.x * 256 + threadIdx.x;   // 524288 threads
  int r = idx >> 5, c = (idx & 31) * 4;
  const float* p = Cp + (size_t)r * 128 + c;
  const size_t pl = (size_t)B_ROWS * 128;
  float4 a = *(const float4*)p;
  float4 b = *(const float4*)(p + pl);
  float4 d2 = *(const float4*)(p + 2 * pl);
  float4 e = *(const float4*)(p + 3 * pl);
  float4 bv = *(const float4*)(badj + c);
  float4 o;
  o.x = a.x + b.x + d2.x + e.x + bv.x;
  o.y = a.y + b.y + d2.y + e.y + bv.y;
  o.z = a.z + b.z + d2.z + e.z + bv.z;
  o.w = a.w + b.w + d2.w + e.w + bv.w;
  *(float4*)(out + (size_t)r * 128 + c) = o;
}

__global__ void cast_x_kernel(const float* __restrict__ x, __bf16* __restrict__ feats) {
  int idx = blockIdx.x * blockDim.x + threadIdx.x;  // B_ROWS*64 threads
  int row = idx >> 6, c8 = (idx & 63) << 3;
  const float4* xp = (const float4*)(x + (size_t)row * 512 + c8);
  float4 a = xp[0], b = xp[1];
  *(bf16x8*)(feats + (size_t)row * LDF + c8) = cvt8(a, b);
}

// Fused fp32->bf16 W-cast with BN folded: W'[n,c]=W[n,c]*sc[c]; badj[n]=bias[n]+sum_c sh[c]*W[n,c]
__global__ void prep_w(const float* __restrict__ W, const float* __restrict__ bias,
                       const float* __restrict__ colsum, const float* __restrict__ colsumsq,
                       const float* __restrict__ gamma, const float* __restrict__ beta,
                       __bf16* __restrict__ Wb, float* __restrict__ badj, int Kd)
{
  const int n = blockIdx.x, t = threadIdx.x;  // 256 threads per row
  const float invB = 1.0f / 16384.0f;
  float accb = 0.f;
  for (int c0 = t * 4; c0 < Kd; c0 += 1024) {
    float4 w = *(const float4*)(W + (size_t)n * Kd + c0);
    float wv[4] = {w.x, w.y, w.z, w.w};
    bf16x4 o;
#pragma unroll
    for (int i = 0; i < 4; ++i) {
      int c = c0 + i;
      float sc = 1.f, sh = 0.f;
      if (c >= 512) {
        int idx = c - 512;
        float mu  = colsum[idx] * invB;
        float var = colsumsq[idx] * invB - mu * mu;
        sc = gamma[idx] * rsqrtf(var + BN_EPS);
        sh = beta[idx] - mu * sc;
      }
      accb += wv[i] * sh;
      o[i] = (__bf16)(wv[i] * sc);
    }
    *(bf16x4*)(Wb + (size_t)n * Kd + c0) = o;
  }
  __shared__ float red[256];
  red[t] = accb;
  __syncthreads();
  for (int s = 128; s > 0; s >>= 1) {
    if (t < s) red[t] += red[t + s];
    __syncthreads();
  }
  if (t == 0) badj[n] = bias[n] + red[0];
}

extern "C" void kernel_launch(void* const* d_in, const int* in_sizes, int n_in,
                              void* d_out, int out_size, void* d_ws, size_t ws_size,
                              hipStream_t stream) {
  const float* x = (const float*)d_in[0];
  const float* Wi[8];
  for (int i = 0; i < 8; ++i) Wi[i] = (const float*)d_in[1 + i];
  const float* b     = (const float*)d_in[9];
  const float* gamma = (const float*)d_in[10];
  const float* beta  = (const float*)d_in[11];
  const float* Wout  = (const float*)d_in[12];
  const float* bout  = (const float*)d_in[13];
  float* out = (float*)d_out;

  char* ws = (char*)d_ws;
  __bf16* feats = (__bf16*)ws;
  size_t off = (size_t)B_ROWS * LDF * 2;
  __bf16* wb[8];
  {
    int d = 512;
    for (int i = 0; i < 8; ++i) { wb[i] = (__bf16*)(ws + off); off += (size_t)256 * d * 2; d += 256; }
  }
  __bf16* woutb = (__bf16*)(ws + off); off += (size_t)128 * 2560 * 2;
  float* Cpart    = (float*)(ws + off); off += (size_t)4 * B_ROWS * 128 * 4;  // 32 MB
  float* colsum   = (float*)(ws + off); off += 8 * 256 * 4;
  float* colsumsq = (float*)(ws + off); off += 8 * 256 * 4;
  float* badj     = (float*)(ws + off); off += 9 * 256 * 4;

  hipMemsetAsync(colsum, 0, 2 * 8 * 256 * 4, stream);

  cast_x_kernel<<<B_ROWS * 64 / 256, 256, 0, stream>>>(x, feats);

  int d = 512;
  for (int i = 0; i < 8; ++i) {
    prep_w<<<256, 256, 0, stream>>>(Wi[i], b + i * 256, colsum, colsumsq,
                                    gamma, beta, wb[i], badj + i * 256, d);
    // grid = 2 bx * 256 by = 512 blocks of 512 threads (16 waves/CU)
    gemm_stage<<<512, 512, 0, stream>>>(feats, wb[i], badj + i * 256,
                                        feats + d, nullptr,
                                        colsum + i * 256, colsumsq + i * 256,
                                        d, d, 1, 1, 0);
    d += 256;
  }
  prep_w<<<128, 256, 0, stream>>>(Wout, bout, colsum, colsumsq,
                                  gamma, beta, woutb, badj + 8 * 256, 2560);
  // final: bxbits=0, SK=4 (Ksplit=640, NT=10): grid = 1 * 4 * 256 by = 1024
  gemm_stage<<<1024, 512, 0, stream>>>(feats, woutb, nullptr,
                                       nullptr, Cpart, nullptr, nullptr,
                                       2560, 640, 0, 0, 2);
  epi_final<<<2048, 256, 0, stream>>>(Cpart, badj + 8 * 256, out);
}